// Round 2
// baseline (82.041 us; speedup 1.0000x reference)
//
#include <hip/hip_runtime.h>

// Log-signature depth 3, d=8, L=256, B=2048.
// Two kernels:
//   1) compute_dx: dx[b][t][c] = x[b][t+1][c]-x[b][t][c] into d_ws,
//      batch stride 2048 floats (8KB aligned rows), t=255 row zeroed
//      (dx=0 is the identity Chen step, so the scan runs 256 clean steps).
//   2) logsig_scan: one wave per batch element, lane l=(i=l>>3, j=l&7).
//      State per lane: s1=S1[i], s2=S2[i][j], s3[k]=S3[i][j][k].
//      Per step (old state on RHS):
//        S3[i][j][k] += (S2[i][j] + (0.5*S1[i] + dx[i]/6)*dx[j]) * dx[k]
//        S2[i][j]    += (S1[i] + 0.5*dx[i]) * dx[j]
//        S1[i]       += dx[i]
//      dx row for the k-loop comes from GLOBAL memory through a
//      wave-uniform pointer (readfirstlane) -> scalar s_load path, so the
//      8 k-FMAs read the row operand from SGPRs (legal: 1 sgpr/VALU op).
//      dxi/dxj come from a transposed padded LDS copy, one ds_read_b128
//      per 4 steps per lane, conflict-free (stride 260 floats).

#define WPB 4
#define LEN 256
#define DCH 8
#define DXSTRIDE 2048                 // floats per batch in the dx workspace
#define TPAD 260                      // padded t-extent of dxT rows
#define OUTSTRIDE (DCH + DCH*DCH + DCH*DCH*DCH)  // 584

typedef float floatv8 __attribute__((ext_vector_type(8)));

__global__ __launch_bounds__(256) void compute_dx(const float* __restrict__ x,
                                                  float* __restrict__ dxg) {
    const int n = blockIdx.x * 256 + threadIdx.x;   // one float4 per thread
    const int wb = n >> 9;                          // batch
    const int f  = n & 511;                         // float4 index within batch
    const float4* x4 = (const float4*)x;
    float4* d4 = (float4*)dxg;
    float4 dv;
    if (f < 510) {
        float4 a = x4[(size_t)wb * 512 + f];
        float4 c = x4[(size_t)wb * 512 + f + 2];
        dv.x = c.x - a.x; dv.y = c.y - a.y; dv.z = c.z - a.z; dv.w = c.w - a.w;
    } else {
        dv.x = 0.f; dv.y = 0.f; dv.z = 0.f; dv.w = 0.f;  // zero pad row t=255
    }
    d4[(size_t)wb * 512 + f] = dv;
}

__global__ __launch_bounds__(256) void logsig_scan(const float* __restrict__ dxg,
                                                   float* __restrict__ out) {
    __shared__ float dxT[WPB][DCH][TPAD];   // transposed dx, padded stride
    __shared__ float s1buf[WPB][8];
    __shared__ float s2buf[WPB][64];

    const int tid  = threadIdx.x;
    const int w    = tid >> 6;
    const int lane = tid & 63;
    const int i    = lane >> 3;
    const int j    = lane & 7;
    const int b    = blockIdx.x * WPB + w;

    // Wave-uniform base pointer for the scalar row loads.
    const int ub = __builtin_amdgcn_readfirstlane(b);
    const float* __restrict__ rowbase = dxg + (size_t)ub * DXSTRIDE;

    // ---- Stage transposed dx into this wave's LDS region (no barrier:
    // each wave touches only its own region; wave-internal LDS ordering
    // is handled by compiler-inserted waitcnts). ----
    const float4* dx4 = (const float4*)(dxg + (size_t)b * DXSTRIDE);
    for (int n4 = lane; n4 < 512; n4 += 64) {
        float4 v = dx4[n4];
        int c0 = (n4 * 4) & 7;        // 0 or 4
        int t  = (n4 * 4) >> 3;
        dxT[w][c0 + 0][t] = v.x;
        dxT[w][c0 + 1][t] = v.y;
        dxT[w][c0 + 2][t] = v.z;
        dxT[w][c0 + 3][t] = v.w;
    }

    // ---- Chen scan: 256 steps (last is the zero row = identity) ----
    float s1 = 0.f, s2 = 0.f;
    float s3[8];
#pragma unroll
    for (int k = 0; k < 8; ++k) s3[k] = 0.f;

    const float c6 = 1.f / 6.f;
    const float* vip = &dxT[w][i][0];
    const float* vjp = &dxT[w][j][0];

    for (int tb = 0; tb < LEN; tb += 4) {
        float4 vi = *(const float4*)(vip + tb);   // dxi for 4 steps (b128)
        float4 vj = *(const float4*)(vjp + tb);   // dxj for 4 steps (b128)
#pragma unroll
        for (int u = 0; u < 4; ++u) {
            floatv8 r = *(const floatv8*)(rowbase + ((tb + u) << 3));  // uniform
            float dxi = (u == 0) ? vi.x : (u == 1) ? vi.y : (u == 2) ? vi.z : vi.w;
            float dxj = (u == 0) ? vj.x : (u == 1) ? vj.y : (u == 2) ? vj.z : vj.w;
            float tt = fmaf(c6, dxi, 0.5f * s1);
            float w3 = fmaf(tt, dxj, s2);
            s3[0] = fmaf(w3, r[0], s3[0]);
            s3[1] = fmaf(w3, r[1], s3[1]);
            s3[2] = fmaf(w3, r[2], s3[2]);
            s3[3] = fmaf(w3, r[3], s3[3]);
            s3[4] = fmaf(w3, r[4], s3[4]);
            s3[5] = fmaf(w3, r[5], s3[5]);
            s3[6] = fmaf(w3, r[6], s3[6]);
            s3[7] = fmaf(w3, r[7], s3[7]);
            float uu = fmaf(0.5f, dxi, s1);
            s2 = fmaf(uu, dxj, s2);
            s1 += dxi;
        }
    }

    // ---- Epilogue: log map (wave-internal LDS exchange, no barrier) ----
    if (j == 0) s1buf[w][i] = s1;
    s2buf[w][lane] = s2;              // s2buf[w][i*8+j]

    float S1r[8], S2rj[8];
#pragma unroll
    for (int k = 0; k < 8; ++k) S1r[k] = s1buf[w][k];
#pragma unroll
    for (int k = 0; k < 8; ++k) S2rj[k] = s2buf[w][j * 8 + k];  // row j of S2
    float s1j = s1buf[w][j];

    float* ob = out + (size_t)b * OUTSTRIDE;
    if (lane < 8) ob[lane] = s1buf[w][lane];          // l1
    ob[8 + lane] = fmaf(-0.5f * s1, s1j, s2);         // l2

    float c3 = (1.f / 3.f) * s1 * s1j;
    float l3[8];
#pragma unroll
    for (int k = 0; k < 8; ++k)
        l3[k] = s3[k] - 0.5f * (s1 * S2rj[k] + s2 * S1r[k]) + c3 * S1r[k];
    float* p3 = ob + 72 + lane * 8;
    *(float4*)(p3)     = make_float4(l3[0], l3[1], l3[2], l3[3]);
    *(float4*)(p3 + 4) = make_float4(l3[4], l3[5], l3[6], l3[7]);
}

extern "C" void kernel_launch(void* const* d_in, const int* in_sizes, int n_in,
                              void* d_out, int out_size, void* d_ws, size_t ws_size,
                              hipStream_t stream) {
    const float* x = (const float*)d_in[0];
    float* out = (float*)d_out;
    float* dxg = (float*)d_ws;
    const int B = in_sizes[0] / (LEN * DCH);          // 2048
    hipLaunchKernelGGL(compute_dx, dim3(B * 2), dim3(256), 0, stream, x, dxg);
    hipLaunchKernelGGL(logsig_scan, dim3(B / WPB), dim3(256), 0, stream, dxg, out);
}

// Round 3
// 73.221 us; speedup vs baseline: 1.1205x; 1.1205x over previous
//
#include <hip/hip_runtime.h>

// Log-signature depth 3, d=8, L=256, B=2048 — single fused kernel.
// One block (4 waves) per batch element. Time split into 4 chunks of 64
// steps; each wave scans its chunk from zero state (dx row t=255 is zeroed,
// a Chen identity step). Chunk signatures are then folded left-to-right by
// wave 0 using Chen's rule:
//   C1 = A1+B1;  C2 = A2+B2+A1⊗B1;  C3 = A3+B3+A1⊗B2+A2⊗B1.
// Lane l = (i=l>>3, j=l&7); per-lane state s1=S1[i], s2=S2[i][j],
// s3[k]=S3[i][j][k]. Per scan step (old state on RHS):
//   S3[i][j][k] += (S2[i][j] + (0.5*S1[i] + dx[i]/6)*dx[j]) * dx[k]
//   S2[i][j]    += (S1[i] + 0.5*dx[i]) * dx[j]
//   S1[i]       += dx[i]

#define LEN 256
#define DCH 8
#define NW 4
#define CHUNK (LEN / NW)      // 64 steps per wave
#define OUTSTRIDE (DCH + DCH*DCH + DCH*DCH*DCH)  // 584

__global__ __launch_bounds__(256) void logsig_fused(const float* __restrict__ x,
                                                    float* __restrict__ out) {
    __shared__ __align__(16) float dxbuf[LEN][DCH];   // 8 KB
    __shared__ __align__(16) float sig1[NW][8];
    __shared__ __align__(16) float sig2[NW][64];
    __shared__ __align__(16) float sig3[NW][512];
    __shared__ __align__(16) float s1buf[8];
    __shared__ __align__(16) float s2buf[64];

    const int tid  = threadIdx.x;
    const int w    = tid >> 6;
    const int lane = tid & 63;
    const int i    = lane >> 3;
    const int j    = lane & 7;
    const int b    = blockIdx.x;

    // ---- Stage dx = x[t+1]-x[t] into LDS (coalesced float4) ----
    const float4* x4 = (const float4*)(x + (size_t)b * (LEN * DCH));
    float4* d4 = (float4*)&dxbuf[0][0];
    for (int f = tid; f < 512; f += 256) {
        float4 dv;
        if (f < 510) {
            float4 a = x4[f];
            float4 c = x4[f + 2];
            dv.x = c.x - a.x; dv.y = c.y - a.y; dv.z = c.z - a.z; dv.w = c.w - a.w;
        } else {
            dv.x = 0.f; dv.y = 0.f; dv.z = 0.f; dv.w = 0.f;  // zero row t=255
        }
        d4[f] = dv;
    }
    __syncthreads();

    // ---- Chunk scan: 64 steps per wave ----
    float s1 = 0.f, s2 = 0.f;
    float s3[8];
#pragma unroll
    for (int k = 0; k < 8; ++k) s3[k] = 0.f;

    const float c6 = 1.f / 6.f;
    const float* base = &dxbuf[w * CHUNK][0];
    for (int tb = 0; tb < CHUNK; tb += 4) {
#pragma unroll
        for (int u = 0; u < 4; ++u) {
            const float* row = base + (tb + u) * 8;
            float4 r0 = *(const float4*)(row);       // broadcast b128
            float4 r1 = *(const float4*)(row + 4);   // broadcast b128
            float dxi = row[i];                      // 8 addr, 8-way bcast
            float dxj = row[j];
            float tt = fmaf(c6, dxi, 0.5f * s1);
            float w3 = fmaf(tt, dxj, s2);
            s3[0] = fmaf(w3, r0.x, s3[0]);
            s3[1] = fmaf(w3, r0.y, s3[1]);
            s3[2] = fmaf(w3, r0.z, s3[2]);
            s3[3] = fmaf(w3, r0.w, s3[3]);
            s3[4] = fmaf(w3, r1.x, s3[4]);
            s3[5] = fmaf(w3, r1.y, s3[5]);
            s3[6] = fmaf(w3, r1.z, s3[6]);
            s3[7] = fmaf(w3, r1.w, s3[7]);
            float uu = fmaf(0.5f, dxi, s1);
            s2 = fmaf(uu, dxj, s2);
            s1 += dxi;
        }
    }

    // ---- Publish chunk signatures ----
    if (j == 0) sig1[w][i] = s1;
    sig2[w][lane] = s2;
    float* sp = &sig3[w][lane * 8];
    *(float4*)(sp)     = make_float4(s3[0], s3[1], s3[2], s3[3]);
    *(float4*)(sp + 4) = make_float4(s3[4], s3[5], s3[6], s3[7]);
    __syncthreads();

    if (w != 0) return;

    // ---- Fold chunks 1..3 into wave 0's registers (A=accum, B=chunk c) ----
    for (int c = 1; c < NW; ++c) {
        float B1i  = sig1[c][i];
        float B1j  = sig1[c][j];
        float B2ij = sig2[c][lane];
        float4 b1a = *(const float4*)&sig1[c][0];
        float4 b1b = *(const float4*)&sig1[c][4];
        const float* b2row = &sig2[c][j * 8];
        float4 b2a = *(const float4*)(b2row);
        float4 b2b = *(const float4*)(b2row + 4);
        const float* b3row = &sig3[c][lane * 8];
        float4 b3a = *(const float4*)(b3row);
        float4 b3b = *(const float4*)(b3row + 4);
        float B1k[8]  = {b1a.x, b1a.y, b1a.z, b1a.w, b1b.x, b1b.y, b1b.z, b1b.w};
        float B2jk[8] = {b2a.x, b2a.y, b2a.z, b2a.w, b2b.x, b2b.y, b2b.z, b2b.w};
        float B3[8]   = {b3a.x, b3a.y, b3a.z, b3a.w, b3b.x, b3b.y, b3b.z, b3b.w};
#pragma unroll
        for (int k = 0; k < 8; ++k)   // uses OLD s1 (A1), OLD s2 (A2)
            s3[k] = s3[k] + B3[k] + s1 * B2jk[k] + s2 * B1k[k];
        s2 = s2 + B2ij + s1 * B1j;    // uses OLD s1
        s1 = s1 + B1i;
    }

    // ---- Log map epilogue (wave-internal LDS exchange) ----
    if (j == 0) s1buf[i] = s1;
    s2buf[lane] = s2;

    float S1r[8], S2rj[8];
#pragma unroll
    for (int k = 0; k < 8; ++k) S1r[k] = s1buf[k];
#pragma unroll
    for (int k = 0; k < 8; ++k) S2rj[k] = s2buf[j * 8 + k];
    float s1j = s1buf[j];

    float* ob = out + (size_t)b * OUTSTRIDE;
    if (lane < 8) ob[lane] = s1buf[lane];            // l1
    ob[8 + lane] = fmaf(-0.5f * s1, s1j, s2);        // l2

    float c3 = (1.f / 3.f) * s1 * s1j;
    float l3[8];
#pragma unroll
    for (int k = 0; k < 8; ++k)
        l3[k] = s3[k] - 0.5f * (s1 * S2rj[k] + s2 * S1r[k]) + c3 * S1r[k];
    float* p3 = ob + 72 + lane * 8;
    *(float4*)(p3)     = make_float4(l3[0], l3[1], l3[2], l3[3]);
    *(float4*)(p3 + 4) = make_float4(l3[4], l3[5], l3[6], l3[7]);
}

extern "C" void kernel_launch(void* const* d_in, const int* in_sizes, int n_in,
                              void* d_out, int out_size, void* d_ws, size_t ws_size,
                              hipStream_t stream) {
    const float* x = (const float*)d_in[0];
    float* out = (float*)d_out;
    const int B = in_sizes[0] / (LEN * DCH);   // 2048
    hipLaunchKernelGGL(logsig_fused, dim3(B), dim3(256), 0, stream, x, out);
}